// Round 11
// baseline (348.278 us; speedup 1.0000x reference)
//
#include <hip/hip_runtime.h>
#include <hip/hip_bf16.h>
#include <math.h>

// PaGCN forward, restructured:
//   h0 = relu(AM ⊙ spmm(adjZ, (M⊙x)@W0) + b0)      (spmm gathers 128 bf16 feats)
//   h1 = relu(AM ⊙ spmm(adjZ, (M⊙h0)@W1) + b1)     (spmm gathers 64 bf16 feats)
//   out = log_softmax(spmm(adj, h1@W2) + b2)        (spmm gathers 40 bf16 feats)
//
// R11: LDS-atomic histogram. R9/R10 falsified ping-pong and MLP theories for
// the 800K-global-atomic hist (stuck ~43-50us => device-scope atomic
// throughput ceiling ~20G/s). New: block g owns a 16384-edge chunk, builds
// its row histogram in LDS (2 row-range passes x 2 rows packed per int =
// 50KB static LDS), LDS atomicAdd return = rank within (row,chunk) ->
// pos_local; per-chunk counts to cnt64[g][N]. scan over G partitions + rp
// scan; scatter: pos = rp[row] + cnt64[e>>14][row] + rank.
// gemm0 back to a plain kernel (fusion surface removed with the atomics).
// ws is 256MB (R9 fill evidence) -> flat layout, no aliasing.
// Carried: no-LDS MFMA gemms, bf16 gather targets, M folded into spmm128,
// multi-edge spmm40/64, 8-deep spmm128 bursts, NaN-laundering clamps.

typedef __attribute__((ext_vector_type(8))) short bf16x8;
typedef __attribute__((ext_vector_type(4))) float f32x4;

#define EPB_LOG2 14
#define EPB (1 << EPB_LOG2)   // edges per hist chunk

__device__ __forceinline__ float rl_f(float v, int j) {
    return __builtin_bit_cast(float,
        __builtin_amdgcn_readlane(__builtin_bit_cast(int, v), j));
}
__device__ __forceinline__ int rl_i(int v, int j) {
    return __builtin_amdgcn_readlane(v, j);
}
__device__ __forceinline__ unsigned short f2bf(float f) {
    unsigned u = __builtin_bit_cast(unsigned, f);
    u += 0x7fffu + ((u >> 16) & 1u);   // round-to-nearest-even
    return (unsigned short)(u >> 16);
}
__device__ __forceinline__ unsigned pack2bf(float lo, float hi) {
    return (unsigned)f2bf(lo) | ((unsigned)f2bf(hi) << 16);
}
__device__ __forceinline__ float bf_lo(unsigned u) {
    return __builtin_bit_cast(float, u << 16);
}
__device__ __forceinline__ float bf_hi(unsigned u) {
    return __builtin_bit_cast(float, u & 0xffff0000u);
}
__device__ __forceinline__ float clampf(float v) {
    return fminf(fmaxf(v, -1e30f), 1e30f);
}

// ---------------- W prep: Wt[n][k] = bf16(W[k][n]), n zero-padded ----------------

__global__ void prep_wt(const float* __restrict__ W0, const float* __restrict__ W1,
                        const float* __restrict__ W2,
                        unsigned short* __restrict__ wt0, unsigned short* __restrict__ wt1,
                        unsigned short* __restrict__ wt2) {
    int idx = blockIdx.x * 256 + threadIdx.x;
    if (idx < 128 * 128) {                       // wt0: [128][128]
        int nn = idx >> 7, k = idx & 127;
        wt0[idx] = f2bf(W0[k * 128 + nn]);
    }
    idx -= 128 * 128;
    if (idx >= 0 && idx < 64 * 128) {            // wt1: [64][128]
        int nn = idx >> 7, k = idx & 127;
        wt1[idx] = f2bf(W1[k * 64 + nn]);
    }
    idx -= 64 * 128;
    if (idx >= 0 && idx < 48 * 64) {             // wt2: [48][64], n>=40 zero
        int nn = idx >> 6, k = idx & 63;
        wt2[idx] = (nn < 40) ? f2bf(W2[k * 40 + nn]) : (unsigned short)0;
    }
}

// ---------------- MFMA GEMM body (no LDS, no barriers) ----------------
// A: lane supplies row m=lane&15, k=q*8..q*8+7 per 32-chunk; B: col n=lane&15;
// D: row=q*4+reg, col=lane&15.  (HW-verified fragment maps.)

template <int K, int COLS, int NTPAD, bool ABF16, bool MSCALE>
__device__ __forceinline__ void gemm_mfma_body(const void* __restrict__ Asrc,
                                               const float* __restrict__ Mv,
                                               const unsigned short* __restrict__ Wt,
                                               unsigned short* __restrict__ outp,
                                               int n, int bid) {
    constexpr int KS = K / 32;
    const int lane = threadIdx.x & 63;
    const int wid = threadIdx.x >> 6;
    const int m15 = lane & 15;
    const int q = lane >> 4;
    const int rA = bid * 64 + wid * 16 + m15;

    bf16x8 a[KS];
    if constexpr (ABF16) {
        const unsigned short* A = (const unsigned short*)Asrc;
#pragma unroll
        for (int ks = 0; ks < KS; ++ks) {
            uint4 z = make_uint4(0u, 0u, 0u, 0u);
            if (rA < n) z = *(const uint4*)(A + (size_t)rA * K + ks * 32 + q * 8);
            a[ks] = __builtin_bit_cast(bf16x8, z);
        }
    } else {
        const float* A = (const float*)Asrc;
        float m = 1.0f;
        if constexpr (MSCALE) { if (rA < n) m = Mv[rA]; }
#pragma unroll
        for (int ks = 0; ks < KS; ++ks) {
            float4 lo = make_float4(0.f, 0.f, 0.f, 0.f);
            float4 hi = make_float4(0.f, 0.f, 0.f, 0.f);
            if (rA < n) {
                lo = *(const float4*)(A + (size_t)rA * K + ks * 32 + q * 8);
                hi = *(const float4*)(A + (size_t)rA * K + ks * 32 + q * 8 + 4);
            }
            union { bf16x8 v; unsigned short u[8]; } pk;
            pk.u[0] = f2bf(lo.x * m); pk.u[1] = f2bf(lo.y * m);
            pk.u[2] = f2bf(lo.z * m); pk.u[3] = f2bf(lo.w * m);
            pk.u[4] = f2bf(hi.x * m); pk.u[5] = f2bf(hi.y * m);
            pk.u[6] = f2bf(hi.z * m); pk.u[7] = f2bf(hi.w * m);
            a[ks] = pk.v;
        }
    }

#pragma unroll
    for (int nt = 0; nt < NTPAD / 16; ++nt) {
        f32x4 acc = {0.f, 0.f, 0.f, 0.f};
        const int bn = nt * 16 + m15;
#pragma unroll
        for (int ks = 0; ks < KS; ++ks) {
            const uint4 z = *(const uint4*)(Wt + (size_t)bn * K + ks * 32 + q * 8);
            const bf16x8 b = __builtin_bit_cast(bf16x8, z);
            acc = __builtin_amdgcn_mfma_f32_16x16x32_bf16(a[ks], b, acc, 0, 0, 0);
        }
        const int gc = nt * 16 + m15;
#pragma unroll
        for (int rr = 0; rr < 4; ++rr) {
            const int gr = bid * 64 + wid * 16 + q * 4 + rr;
            bool ok = gr < n;
            if constexpr (NTPAD != COLS) ok = ok && (gc < COLS);
            if (ok) outp[(size_t)gr * COLS + gc] = f2bf(clampf(acc[rr]));
        }
    }
}

template <int K, int COLS, int NTPAD, bool ABF16, bool MSCALE>
__launch_bounds__(256)
__global__ void gemm_mfma(const void* __restrict__ A, const float* __restrict__ Mv,
                          const unsigned short* __restrict__ Wt,
                          unsigned short* __restrict__ out, int n) {
    gemm_mfma_body<K, COLS, NTPAD, ABF16, MSCALE>(A, Mv, Wt, out, n, blockIdx.x);
}

// ---------------- LDS-atomic histogram + rank ----------------
// Block g owns edges [g*EPB, (g+1)*EPB). Two row-range passes; 2 rows packed
// per int (low/high 16-bit counts). LDS atomicAdd return = rank within
// (row, chunk). Writes cnt64[g][i] = count of row i in chunk g.

__launch_bounds__(256)
__global__ void hist_lds(const int* __restrict__ row, int* __restrict__ cnt64,
                         int* __restrict__ pos_local, int n, int E) {
    __shared__ int lds[12544];                 // 50.2KB; rows n<=50176 supported
    const int g = blockIdx.x;
    const int t = threadIdx.x;
    const int e0 = g << EPB_LOG2;
    const int e1 = min(e0 + EPB, E);
    const int halfn = (n + 1) >> 1;            // rows per pass

    for (int pass = 0; pass < 2; ++pass) {
        const int rlo = pass * halfn;
        const int rhi = min(rlo + halfn, n);
        const int bins = (rhi - rlo + 1) >> 1;
        for (int i = t; i < bins; i += 256) lds[i] = 0;
        __syncthreads();
        for (int e = e0 + t; e < e1; e += 256) {
            const int r = row[e];
            if (r >= rlo && r < rhi) {
                const int lr = r - rlo;
                const int old = atomicAdd(&lds[lr >> 1], (lr & 1) ? 0x10000 : 1);
                pos_local[e] = (lr & 1) ? (old >> 16) : (old & 0xffff);
            }
        }
        __syncthreads();
        for (int i = t; i < rhi - rlo; i += 256) {
            const int v = lds[i >> 1];
            cnt64[(size_t)g * n + rlo + i] = (i & 1) ? (v >> 16) : (v & 0xffff);
        }
        __syncthreads();
    }
}

// ---------------- scan over partitions + block scan of row totals ----------------
// In-place: cnt64[g][i] -> exclusive prefix over g; rp gets block-local
// exclusive prefix of row totals; bsums gets block sums.

__global__ void scan_part_g(int* __restrict__ cnt64, int* __restrict__ rp,
                            int* __restrict__ bsums, int n, int G) {
    __shared__ int sdata[256];
    const int t = threadIdx.x;
    const int base = blockIdx.x * 1024 + t * 4;
    int v[4];
#pragma unroll
    for (int i = 0; i < 4; ++i) {
        const int idx = base + i;
        int s = 0;
        if (idx < n) {
            for (int x = 0; x < G; ++x) {
                const int c = cnt64[(size_t)x * n + idx];
                cnt64[(size_t)x * n + idx] = s;   // exclusive prefix over chunks
                s += c;
            }
        }
        v[i] = s;                                 // row total
    }
    int tsum = v[0] + v[1] + v[2] + v[3];
    sdata[t] = tsum;
    __syncthreads();
    for (int off = 1; off < 256; off <<= 1) {
        int x = (t >= off) ? sdata[t - off] : 0;
        __syncthreads();
        sdata[t] += x;
        __syncthreads();
    }
    int run = sdata[t] - tsum;
    if (t == 255) bsums[blockIdx.x] = sdata[t];
#pragma unroll
    for (int i = 0; i < 4; ++i) {
        if (base + i < n) rp[base + i] = run;
        run += v[i];
    }
}

__global__ void scan_top(int* __restrict__ bs, int nb) {
    int t = threadIdx.x;
    int orig = (t < nb) ? bs[t] : 0;
    int v = orig;
#pragma unroll
    for (int off = 1; off < 64; off <<= 1) {
        int x = __shfl_up(v, off);
        if (t >= off) v += x;
    }
    if (t < nb) bs[t] = v - orig;
}

__global__ void scan_add(int* __restrict__ rp, const int* __restrict__ bs,
                         int n, int total) {
    int i = blockIdx.x * blockDim.x + threadIdx.x;
    if (i < n) rp[i] += bs[i >> 10];
    if (i == 0) rp[n] = total;
}

// ---------------- scatter (atomic-free, 4 edges/thread) ----------------
// pos = rp[row] + cnt64[g][row] + rank,  g = e >> EPB_LOG2 (block-constant
// mostly -> cnt64 slice is L2-hot).

__global__ void scatter_kernel(const int* __restrict__ row, const int* __restrict__ col,
                               const float* __restrict__ vA, const float* __restrict__ vZ,
                               const int* __restrict__ rp, const int* __restrict__ cnt64,
                               const int* __restrict__ pos_local,
                               float* __restrict__ packed, int E, int n) {
    const int base = blockIdx.x * 1024 + threadIdx.x;
#pragma unroll
    for (int u = 0; u < 4; ++u) {
        const int e = base + u * 256;
        if (e >= E) continue;
        const int g = e >> EPB_LOG2;
        const int r = row[e];
        const int pos = rp[r] + cnt64[(size_t)g * n + r] + pos_local[e];
        float3 pk;
        pk.x = __int_as_float(col[e]);
        pk.y = vZ[e];
        pk.z = vA[e];
        *(float3*)&packed[(size_t)3 * pos] = pk;
    }
}

// ---------------- SpMM F=128: wave/row, 8-deep bursts; out = M⊙relu(...) bf16 ----------------

__launch_bounds__(256)
__global__ void spmm128_kernel(const float* __restrict__ packed,
                               const int* __restrict__ rp, const unsigned short* __restrict__ X,
                               const float* __restrict__ AM, const float* __restrict__ Mv,
                               const float* __restrict__ bias,
                               unsigned short* __restrict__ out, int n) {
    const int lane = threadIdx.x & 63;
    const int r = (int)((blockIdx.x * (unsigned)blockDim.x + threadIdx.x) >> 6);
    if (r >= n) return;
    const int s = __builtin_amdgcn_readfirstlane(rp[r]);
    const int e = __builtin_amdgcn_readfirstlane(rp[r + 1]);

    float acc0 = 0.0f, acc1 = 0.0f;
    for (int base = s; base < e; base += 64) {
        const int nn = min(64, e - base);
        int ci = 0; float vf = 0.0f;
        if (lane < nn) {
            const float3 pk = *(const float3*)&packed[(size_t)3 * (base + lane)];
            ci = __builtin_bit_cast(int, pk.x);
            vf = pk.y;
        }
        int j = 0;
        for (; j + 8 <= nn; j += 8) {
            unsigned u[8];
#pragma unroll
            for (int q = 0; q < 8; ++q) {
                const int cq = rl_i(ci, j + q);
                u[q] = *(const unsigned*)(X + (size_t)cq * 128 + lane * 2);
            }
#pragma unroll
            for (int q = 0; q < 8; ++q) {
                const float vq = rl_f(vf, j + q);
                acc0 += vq * bf_lo(u[q]);
                acc1 += vq * bf_hi(u[q]);
            }
        }
        for (; j < nn; ++j) {
            const int cq = rl_i(ci, j);
            const float vq = rl_f(vf, j);
            const unsigned u = *(const unsigned*)(X + (size_t)cq * 128 + lane * 2);
            acc0 += vq * bf_lo(u);
            acc1 += vq * bf_hi(u);
        }
    }

    const float am = AM[r];
    const float mr = Mv[r];   // fold M (>=0): M⊙relu(y) = relu(M⊙y)
    const float o0 = fminf(fmaxf((acc0 * am + bias[2 * lane]) * mr, 0.0f), 1e30f);
    const float o1 = fminf(fmaxf((acc1 * am + bias[2 * lane + 1]) * mr, 0.0f), 1e30f);
    ((unsigned*)out)[(size_t)r * 64 + lane] = pack2bf(o0, o1);
}

// ---------------- SpMM F=64: 2 edges/wave; out = relu(...) bf16 ----------------

__launch_bounds__(256)
__global__ void spmm64_kernel(const float* __restrict__ packed,
                              const int* __restrict__ rp, const unsigned short* __restrict__ X,
                              const float* __restrict__ AM, const float* __restrict__ bias,
                              unsigned short* __restrict__ out, int n) {
    const int lane = threadIdx.x & 63;
    const int g = lane >> 5;
    const int ls = lane & 31;
    const int r = (int)((blockIdx.x * (unsigned)blockDim.x + threadIdx.x) >> 6);
    if (r >= n) return;
    const int s = __builtin_amdgcn_readfirstlane(rp[r]);
    const int e = __builtin_amdgcn_readfirstlane(rp[r + 1]);

    float acc0 = 0.0f, acc1 = 0.0f;
    for (int base = s; base < e; base += 64) {
        const int nn = min(64, e - base);
        int ci = 0; float vf = 0.0f;
        if (lane < nn) {
            const float3 pk = *(const float3*)&packed[(size_t)3 * (base + lane)];
            ci = __builtin_bit_cast(int, pk.x);
            vf = pk.y;
        }
        for (int j = 0; j < nn; j += 8) {
#pragma unroll
            for (int q = 0; q < 4; ++q) {
                const int jj = j + 2 * q + g;
                const bool ok = jj < nn;
                const int idx = jj & 63;
                const int c = __shfl(ci, idx);
                const float v = __shfl(vf, idx);
                if (ok) {
                    const unsigned u = *(const unsigned*)(X + (size_t)c * 64 + ls * 2);
                    acc0 += v * bf_lo(u);
                    acc1 += v * bf_hi(u);
                }
            }
        }
    }
    acc0 += __shfl_xor(acc0, 32);
    acc1 += __shfl_xor(acc1, 32);

    if (lane < 32) {
        const float am = AM[r];
        const float o0 = fminf(fmaxf(acc0 * am + bias[2 * ls], 0.0f), 1e30f);
        const float o1 = fminf(fmaxf(acc1 * am + bias[2 * ls + 1], 0.0f), 1e30f);
        ((unsigned*)out)[(size_t)r * 32 + ls] = pack2bf(o0, o1);
    }
}

// ---------------- SpMM F=40 + log_softmax: 3 edges/wave ----------------

__launch_bounds__(256)
__global__ void spmm40_kernel(const float* __restrict__ packed,
                              const int* __restrict__ rp, const unsigned short* __restrict__ X,
                              const float* __restrict__ bias,
                              float* __restrict__ out, int n) {
    const int lane = threadIdx.x & 63;
    const int g = lane / 20;
    const int ls = lane - 20 * g;
    const bool active = g < 3;
    const int r = (int)((blockIdx.x * (unsigned)blockDim.x + threadIdx.x) >> 6);
    if (r >= n) return;
    const int s = __builtin_amdgcn_readfirstlane(rp[r]);
    const int e = __builtin_amdgcn_readfirstlane(rp[r + 1]);

    float acc0 = 0.0f, acc1 = 0.0f;
    for (int base = s; base < e; base += 64) {
        const int nn = min(64, e - base);
        int ci = 0; float vf = 0.0f;
        if (lane < nn) {
            const float3 pk = *(const float3*)&packed[(size_t)3 * (base + lane)];
            ci = __builtin_bit_cast(int, pk.x);
            vf = pk.z;                   // adj (not adjZ) values
        }
        for (int j = 0; j < nn; j += 12) {
#pragma unroll
            for (int q = 0; q < 4; ++q) {
                const int jj = j + 3 * q + g;
                const bool ok = active && jj < nn;
                const int idx = jj & 63;
                const int c = __shfl(ci, idx);
                const float v = __shfl(vf, idx);
                if (ok) {
                    const unsigned u = *(const unsigned*)(X + (size_t)c * 40 + ls * 2);
                    acc0 += v * bf_lo(u);
                    acc1 += v * bf_hi(u);
                }
            }
        }
    }
    {
        const float a1 = __shfl(acc0, (lane + 20) & 63);
        const float a2 = __shfl(acc0, (lane + 40) & 63);
        const float b1 = __shfl(acc1, (lane + 20) & 63);
        const float b2 = __shfl(acc1, (lane + 40) & 63);
        acc0 += a1 + a2;
        acc1 += b1 + b2;
    }

    const bool own = lane < 20;
    const float vv0 = own ? fminf(fmaxf(acc0 + bias[2 * ls], -1e30f), 1e30f) : -INFINITY;
    const float vv1 = own ? fminf(fmaxf(acc1 + bias[2 * ls + 1], -1e30f), 1e30f) : -INFINITY;
    float mx = fmaxf(vv0, vv1);
#pragma unroll
    for (int off = 32; off > 0; off >>= 1) mx = fmaxf(mx, __shfl_xor(mx, off));
    float sum = own ? (expf(vv0 - mx) + expf(vv1 - mx)) : 0.0f;
#pragma unroll
    for (int off = 32; off > 0; off >>= 1) sum += __shfl_xor(sum, off);
    if (own) {
        const float lse = mx + logf(sum);
        *(float2*)(out + (size_t)r * 40 + ls * 2) = make_float2(vv0 - lse, vv1 - lse);
    }
}

// ---------------- launch ----------------

extern "C" void kernel_launch(void* const* d_in, const int* in_sizes, int n_in,
                              void* d_out, int out_size, void* d_ws, size_t ws_size,
                              hipStream_t stream) {
    const float* x    = (const float*)d_in[0];
    const float* M    = (const float*)d_in[1];
    const float* AM   = (const float*)d_in[2];
    const float* adjv = (const float*)d_in[3];
    const float* adjZ = (const float*)d_in[4];
    const float* W0   = (const float*)d_in[5];
    const float* b0   = (const float*)d_in[6];
    const float* W1   = (const float*)d_in[7];
    const float* b1   = (const float*)d_in[8];
    const float* W2   = (const float*)d_in[9];
    const float* b2   = (const float*)d_in[10];
    const int* row    = (const int*)d_in[11];
    const int* col    = (const int*)d_in[12];
    float* out = (float*)d_out;

    const int n = in_sizes[1];   // N
    const int E = in_sizes[3];   // edges
    const int G = (E + EPB - 1) >> EPB_LOG2;    // hist chunks (49 @ E=800K)

    // flat workspace layout (ws is 256MB; ~62MB used, no aliasing):
    char* p = (char*)d_ws;
    unsigned short* t_buf = (unsigned short*)p;  p += (size_t)n * 128 * 2;   // 12.8MB
    unsigned short* h_buf = (unsigned short*)p;  p += (size_t)n * 128 * 2;   // 12.8MB
    unsigned short* wt0   = (unsigned short*)p;  p += 128 * 128 * 2;
    unsigned short* wt1   = (unsigned short*)p;  p += 64 * 128 * 2;
    unsigned short* wt2   = (unsigned short*)p;  p += 48 * 64 * 2 + 64;
    int* cnt64     = (int*)p;                    p += (size_t)G * n * 4;     // 9.8MB
    int* rp        = (int*)p;                    p += (size_t)(n + 1) * 4;
    int* bsums     = (int*)p;                    p += 64 * 4;
    int* pos_local = (int*)p;                    p += (size_t)E * 4;         // 3.2MB
    float* packed  = (float*)p;                  /* E*3 floats, 9.6MB */

    prep_wt<<<(128 * 128 + 64 * 128 + 48 * 64 + 255) / 256, 256, 0, stream>>>(
        W0, W1, W2, wt0, wt1, wt2);

    const int gemmBlocks = (n + 63) / 64;

    // CSR build: LDS histogram (+ranks), partition scan, rp scan, scatter
    hist_lds<<<G, 256, 0, stream>>>(row, cnt64, pos_local, n, E);
    gemm_mfma<128, 128, 128, false, true><<<gemmBlocks, 256, 0, stream>>>(x, M, wt0, t_buf, n);
    const int nblk = (n + 1023) >> 10;  // <=64 required by scan_top
    scan_part_g<<<nblk, 256, 0, stream>>>(cnt64, rp, bsums, n, G);
    scan_top<<<1, 64, 0, stream>>>(bsums, nblk);
    scan_add<<<(n + 255) / 256, 256, 0, stream>>>(rp, bsums, n, E);
    scatter_kernel<<<(E + 1023) / 1024, 256, 0, stream>>>(row, col, adjv, adjZ, rp, cnt64,
                                                          pos_local, packed, E, n);

    const int spmmBlocks = (n + 3) / 4;   // 4 rows (waves) per block

    // layer 0 aggregate: h_buf = M⊙relu(AM⊙agg+b0) bf16
    spmm128_kernel<<<spmmBlocks, 256, 0, stream>>>(packed, rp, t_buf, AM, M, b0, h_buf, n);
    // layer 1: t_buf = h_buf@W1 bf16 (M already folded)
    gemm_mfma<128, 64, 64, true, false><<<gemmBlocks, 256, 0, stream>>>(h_buf, nullptr, wt1,
                                                                        t_buf, n);
    spmm64_kernel<<<spmmBlocks, 256, 0, stream>>>(packed, rp, t_buf, AM, b1, h_buf, n);
    // layer 2: t_buf = h1@W2 bf16 (stride 40)
    gemm_mfma<64, 40, 48, true, false><<<gemmBlocks, 256, 0, stream>>>(h_buf, nullptr, wt2,
                                                                       t_buf, n);
    spmm40_kernel<<<spmmBlocks, 256, 0, stream>>>(packed, rp, t_buf, b2, out, n);
}

// Round 12
// 334.423 us; speedup vs baseline: 1.0414x; 1.0414x over previous
//
#include <hip/hip_runtime.h>
#include <hip/hip_bf16.h>
#include <math.h>

// PaGCN forward, restructured:
//   h0 = relu(AM ⊙ spmm(adjZ, (M⊙x)@W0) + b0)      (spmm gathers 128 bf16 feats)
//   h1 = relu(AM ⊙ spmm(adjZ, (M⊙h0)@W1) + b1)     (spmm gathers 64 bf16 feats)
//   out = log_softmax(spmm(adj, h1@W2) + b2)        (spmm gathers 40 bf16 feats)
//
// R12: R11's LDS-atomic histogram with a SATURATING grid. R11 failed on grid
// size (G=49 blocks -> 1.9% occupancy, 55us). Now EPB=4096 -> G=196 blocks;
// counts/ranks < 4096 -> ushort cnt16[G][N] (19.6MB) + ushort pos_local.
// prep_wt fused into the hist launch; gemm0 fused into scan_part_g (memory-
// bound scan + MFMA-bound gemm share the machine). Scan inner loop uses
// ushort4 (4 rows/thread/iter, coalesced).
// Carried: no-LDS MFMA gemms, bf16 gather targets, M folded into spmm128,
// multi-edge spmm40/64, 8-deep spmm128 bursts, NaN-laundering clamps.

typedef __attribute__((ext_vector_type(8))) short bf16x8;
typedef __attribute__((ext_vector_type(4))) float f32x4;

#define EPB_LOG2 12
#define EPB (1 << EPB_LOG2)   // 4096 edges per hist chunk

__device__ __forceinline__ float rl_f(float v, int j) {
    return __builtin_bit_cast(float,
        __builtin_amdgcn_readlane(__builtin_bit_cast(int, v), j));
}
__device__ __forceinline__ int rl_i(int v, int j) {
    return __builtin_amdgcn_readlane(v, j);
}
__device__ __forceinline__ unsigned short f2bf(float f) {
    unsigned u = __builtin_bit_cast(unsigned, f);
    u += 0x7fffu + ((u >> 16) & 1u);   // round-to-nearest-even
    return (unsigned short)(u >> 16);
}
__device__ __forceinline__ unsigned pack2bf(float lo, float hi) {
    return (unsigned)f2bf(lo) | ((unsigned)f2bf(hi) << 16);
}
__device__ __forceinline__ float bf_lo(unsigned u) {
    return __builtin_bit_cast(float, u << 16);
}
__device__ __forceinline__ float bf_hi(unsigned u) {
    return __builtin_bit_cast(float, u & 0xffff0000u);
}
__device__ __forceinline__ float clampf(float v) {
    return fminf(fmaxf(v, -1e30f), 1e30f);
}

// ---------------- MFMA GEMM body (no LDS, no barriers) ----------------
// A: lane supplies row m=lane&15, k=q*8..q*8+7 per 32-chunk; B: col n=lane&15;
// D: row=q*4+reg, col=lane&15.  (HW-verified fragment maps.)

template <int K, int COLS, int NTPAD, bool ABF16, bool MSCALE>
__device__ __forceinline__ void gemm_mfma_body(const void* __restrict__ Asrc,
                                               const float* __restrict__ Mv,
                                               const unsigned short* __restrict__ Wt,
                                               unsigned short* __restrict__ outp,
                                               int n, int bid) {
    constexpr int KS = K / 32;
    const int lane = threadIdx.x & 63;
    const int wid = threadIdx.x >> 6;
    const int m15 = lane & 15;
    const int q = lane >> 4;
    const int rA = bid * 64 + wid * 16 + m15;

    bf16x8 a[KS];
    if constexpr (ABF16) {
        const unsigned short* A = (const unsigned short*)Asrc;
#pragma unroll
        for (int ks = 0; ks < KS; ++ks) {
            uint4 z = make_uint4(0u, 0u, 0u, 0u);
            if (rA < n) z = *(const uint4*)(A + (size_t)rA * K + ks * 32 + q * 8);
            a[ks] = __builtin_bit_cast(bf16x8, z);
        }
    } else {
        const float* A = (const float*)Asrc;
        float m = 1.0f;
        if constexpr (MSCALE) { if (rA < n) m = Mv[rA]; }
#pragma unroll
        for (int ks = 0; ks < KS; ++ks) {
            float4 lo = make_float4(0.f, 0.f, 0.f, 0.f);
            float4 hi = make_float4(0.f, 0.f, 0.f, 0.f);
            if (rA < n) {
                lo = *(const float4*)(A + (size_t)rA * K + ks * 32 + q * 8);
                hi = *(const float4*)(A + (size_t)rA * K + ks * 32 + q * 8 + 4);
            }
            union { bf16x8 v; unsigned short u[8]; } pk;
            pk.u[0] = f2bf(lo.x * m); pk.u[1] = f2bf(lo.y * m);
            pk.u[2] = f2bf(lo.z * m); pk.u[3] = f2bf(lo.w * m);
            pk.u[4] = f2bf(hi.x * m); pk.u[5] = f2bf(hi.y * m);
            pk.u[6] = f2bf(hi.z * m); pk.u[7] = f2bf(hi.w * m);
            a[ks] = pk.v;
        }
    }

#pragma unroll
    for (int nt = 0; nt < NTPAD / 16; ++nt) {
        f32x4 acc = {0.f, 0.f, 0.f, 0.f};
        const int bn = nt * 16 + m15;
#pragma unroll
        for (int ks = 0; ks < KS; ++ks) {
            const uint4 z = *(const uint4*)(Wt + (size_t)bn * K + ks * 32 + q * 8);
            const bf16x8 b = __builtin_bit_cast(bf16x8, z);
            acc = __builtin_amdgcn_mfma_f32_16x16x32_bf16(a[ks], b, acc, 0, 0, 0);
        }
        const int gc = nt * 16 + m15;
#pragma unroll
        for (int rr = 0; rr < 4; ++rr) {
            const int gr = bid * 64 + wid * 16 + q * 4 + rr;
            bool ok = gr < n;
            if constexpr (NTPAD != COLS) ok = ok && (gc < COLS);
            if (ok) outp[(size_t)gr * COLS + gc] = f2bf(clampf(acc[rr]));
        }
    }
}

template <int K, int COLS, int NTPAD, bool ABF16, bool MSCALE>
__launch_bounds__(256)
__global__ void gemm_mfma(const void* __restrict__ A, const float* __restrict__ Mv,
                          const unsigned short* __restrict__ Wt,
                          unsigned short* __restrict__ out, int n) {
    gemm_mfma_body<K, COLS, NTPAD, ABF16, MSCALE>(A, Mv, Wt, out, n, blockIdx.x);
}

// ---------------- hist (LDS atomics) + fused W-prep ----------------
// Blocks [0,G): block g owns edges [g*4096, (g+1)*4096). Row histogram in
// LDS, 2 row-range passes, 2 rows packed per int (16-bit counts; count <=
// 4096). atomicAdd return = rank within (row,chunk) -> pos_local (ushort).
// cnt16[g][i] = count of row i in chunk g.
// Blocks [G,...): Wt[n][k] = bf16(W[k][n]) transpose-convert.

__launch_bounds__(256)
__global__ void hist_prep(const int* __restrict__ row, unsigned short* __restrict__ cnt16,
                          unsigned short* __restrict__ pos_local, int n, int E, int G,
                          const float* __restrict__ W0, const float* __restrict__ W1,
                          const float* __restrict__ W2,
                          unsigned short* __restrict__ wt0, unsigned short* __restrict__ wt1,
                          unsigned short* __restrict__ wt2) {
    __shared__ int lds[12544];                 // 50.2KB; supports n <= 50176
    const int b = blockIdx.x;
    if (b >= G) {
        int idx = (b - G) * 256 + threadIdx.x;
        if (idx < 128 * 128) {                       // wt0: [128][128]
            int nn = idx >> 7, k = idx & 127;
            wt0[idx] = f2bf(W0[k * 128 + nn]);
        }
        idx -= 128 * 128;
        if (idx >= 0 && idx < 64 * 128) {            // wt1: [64][128]
            int nn = idx >> 7, k = idx & 127;
            wt1[idx] = f2bf(W1[k * 64 + nn]);
        }
        idx -= 64 * 128;
        if (idx >= 0 && idx < 48 * 64) {             // wt2: [48][64], n>=40 zero
            int nn = idx >> 6, k = idx & 63;
            wt2[idx] = (nn < 40) ? f2bf(W2[k * 40 + nn]) : (unsigned short)0;
        }
        return;
    }

    const int g = b;
    const int t = threadIdx.x;
    const int e0 = g << EPB_LOG2;
    const int e1 = min(e0 + EPB, E);
    const int halfn = (n + 1) >> 1;            // rows per pass

    for (int pass = 0; pass < 2; ++pass) {
        const int rlo = pass * halfn;
        const int rhi = min(rlo + halfn, n);
        const int bins = (rhi - rlo + 1) >> 1;
        for (int i = t; i < bins; i += 256) lds[i] = 0;
        __syncthreads();
        for (int e = e0 + t; e < e1; e += 256) {
            const int r = row[e];
            if (r >= rlo && r < rhi) {
                const int lr = r - rlo;
                const int old = atomicAdd(&lds[lr >> 1], (lr & 1) ? 0x10000 : 1);
                pos_local[e] = (unsigned short)((lr & 1) ? (old >> 16) : (old & 0xffff));
            }
        }
        __syncthreads();
        for (int i = t; i < rhi - rlo; i += 256) {
            const int v = lds[i >> 1];
            cnt16[(size_t)g * n + rlo + i] =
                (unsigned short)((i & 1) ? (v >> 16) : (v & 0xffff));
        }
        __syncthreads();
    }
}

// ---------------- scan over chunks + block scan of row totals, fused gemm0 ----------------
// Blocks [0,nblk): in-place cnt16[g][i] -> exclusive prefix over g; rp gets
// block-local exclusive prefix of row totals; bsums block sums.
// Blocks [nblk,...): gemm0 (t_buf = bf16((M⊙x)@W0)).

__launch_bounds__(256)
__global__ void scan_gemm0(unsigned short* __restrict__ cnt16, int* __restrict__ rp,
                           int* __restrict__ bsums, int n, int G, int nblk,
                           const float* __restrict__ x, const float* __restrict__ Mv,
                           const unsigned short* __restrict__ wt0,
                           unsigned short* __restrict__ t_buf) {
    __shared__ int sdata[256];
    const int b = blockIdx.x;
    if (b >= nblk) {
        gemm_mfma_body<128, 128, 128, false, true>(x, Mv, wt0, t_buf, n, b - nblk);
        return;
    }
    const int t = threadIdx.x;
    const int base = b * 1024 + t * 4;
    int v0 = 0, v1 = 0, v2 = 0, v3 = 0;
    if (base + 3 < n && (n & 3) == 0) {
        for (int g = 0; g < G; ++g) {
            ushort4* p = (ushort4*)&cnt16[(size_t)g * n + base];
            const ushort4 c = *p;
            ushort4 w;
            w.x = (unsigned short)v0; w.y = (unsigned short)v1;
            w.z = (unsigned short)v2; w.w = (unsigned short)v3;
            *p = w;
            v0 += c.x; v1 += c.y; v2 += c.z; v3 += c.w;
        }
    } else {
        int vv[4] = {0, 0, 0, 0};
        for (int g = 0; g < G; ++g) {
#pragma unroll
            for (int i = 0; i < 4; ++i) {
                const int idx = base + i;
                if (idx < n) {
                    const int c = cnt16[(size_t)g * n + idx];
                    cnt16[(size_t)g * n + idx] = (unsigned short)vv[i];
                    vv[i] += c;
                }
            }
        }
        v0 = vv[0]; v1 = vv[1]; v2 = vv[2]; v3 = vv[3];
    }
    const int tsum = v0 + v1 + v2 + v3;
    sdata[t] = tsum;
    __syncthreads();
    for (int off = 1; off < 256; off <<= 1) {
        int xx = (t >= off) ? sdata[t - off] : 0;
        __syncthreads();
        sdata[t] += xx;
        __syncthreads();
    }
    int run = sdata[t] - tsum;
    if (t == 255) bsums[b] = sdata[t];
    if (base < n) rp[base] = run;
    run += v0;
    if (base + 1 < n) rp[base + 1] = run;
    run += v1;
    if (base + 2 < n) rp[base + 2] = run;
    run += v2;
    if (base + 3 < n) rp[base + 3] = run;
}

__global__ void scan_top(int* __restrict__ bs, int nb) {
    int t = threadIdx.x;
    int orig = (t < nb) ? bs[t] : 0;
    int v = orig;
#pragma unroll
    for (int off = 1; off < 64; off <<= 1) {
        int x = __shfl_up(v, off);
        if (t >= off) v += x;
    }
    if (t < nb) bs[t] = v - orig;
}

__global__ void scan_add(int* __restrict__ rp, const int* __restrict__ bs,
                         int n, int total) {
    int i = blockIdx.x * blockDim.x + threadIdx.x;
    if (i < n) rp[i] += bs[i >> 10];
    if (i == 0) rp[n] = total;
}

// ---------------- scatter (atomic-free, 4 edges/thread) ----------------
// pos = rp[row] + cnt16[g][row] + rank,  g = e >> 12 (block-quasi-constant
// -> 100KB cnt16 slice is L2-hot).

__global__ void scatter_kernel(const int* __restrict__ row, const int* __restrict__ col,
                               const float* __restrict__ vA, const float* __restrict__ vZ,
                               const int* __restrict__ rp, const unsigned short* __restrict__ cnt16,
                               const unsigned short* __restrict__ pos_local,
                               float* __restrict__ packed, int E, int n) {
    const int base = blockIdx.x * 1024 + threadIdx.x;
#pragma unroll
    for (int u = 0; u < 4; ++u) {
        const int e = base + u * 256;
        if (e >= E) continue;
        const int g = e >> EPB_LOG2;
        const int r = row[e];
        const int pos = rp[r] + (int)cnt16[(size_t)g * n + r] + (int)pos_local[e];
        float3 pk;
        pk.x = __int_as_float(col[e]);
        pk.y = vZ[e];
        pk.z = vA[e];
        *(float3*)&packed[(size_t)3 * pos] = pk;
    }
}

// ---------------- SpMM F=128: wave/row, 8-deep bursts; out = M⊙relu(...) bf16 ----------------

__launch_bounds__(256)
__global__ void spmm128_kernel(const float* __restrict__ packed,
                               const int* __restrict__ rp, const unsigned short* __restrict__ X,
                               const float* __restrict__ AM, const float* __restrict__ Mv,
                               const float* __restrict__ bias,
                               unsigned short* __restrict__ out, int n) {
    const int lane = threadIdx.x & 63;
    const int r = (int)((blockIdx.x * (unsigned)blockDim.x + threadIdx.x) >> 6);
    if (r >= n) return;
    const int s = __builtin_amdgcn_readfirstlane(rp[r]);
    const int e = __builtin_amdgcn_readfirstlane(rp[r + 1]);

    float acc0 = 0.0f, acc1 = 0.0f;
    for (int base = s; base < e; base += 64) {
        const int nn = min(64, e - base);
        int ci = 0; float vf = 0.0f;
        if (lane < nn) {
            const float3 pk = *(const float3*)&packed[(size_t)3 * (base + lane)];
            ci = __builtin_bit_cast(int, pk.x);
            vf = pk.y;
        }
        int j = 0;
        for (; j + 8 <= nn; j += 8) {
            unsigned u[8];
#pragma unroll
            for (int q = 0; q < 8; ++q) {
                const int cq = rl_i(ci, j + q);
                u[q] = *(const unsigned*)(X + (size_t)cq * 128 + lane * 2);
            }
#pragma unroll
            for (int q = 0; q < 8; ++q) {
                const float vq = rl_f(vf, j + q);
                acc0 += vq * bf_lo(u[q]);
                acc1 += vq * bf_hi(u[q]);
            }
        }
        for (; j < nn; ++j) {
            const int cq = rl_i(ci, j);
            const float vq = rl_f(vf, j);
            const unsigned u = *(const unsigned*)(X + (size_t)cq * 128 + lane * 2);
            acc0 += vq * bf_lo(u);
            acc1 += vq * bf_hi(u);
        }
    }

    const float am = AM[r];
    const float mr = Mv[r];   // fold M (>=0): M⊙relu(y) = relu(M⊙y)
    const float o0 = fminf(fmaxf((acc0 * am + bias[2 * lane]) * mr, 0.0f), 1e30f);
    const float o1 = fminf(fmaxf((acc1 * am + bias[2 * lane + 1]) * mr, 0.0f), 1e30f);
    ((unsigned*)out)[(size_t)r * 64 + lane] = pack2bf(o0, o1);
}

// ---------------- SpMM F=64: 2 edges/wave; out = relu(...) bf16 ----------------

__launch_bounds__(256)
__global__ void spmm64_kernel(const float* __restrict__ packed,
                              const int* __restrict__ rp, const unsigned short* __restrict__ X,
                              const float* __restrict__ AM, const float* __restrict__ bias,
                              unsigned short* __restrict__ out, int n) {
    const int lane = threadIdx.x & 63;
    const int g = lane >> 5;
    const int ls = lane & 31;
    const int r = (int)((blockIdx.x * (unsigned)blockDim.x + threadIdx.x) >> 6);
    if (r >= n) return;
    const int s = __builtin_amdgcn_readfirstlane(rp[r]);
    const int e = __builtin_amdgcn_readfirstlane(rp[r + 1]);

    float acc0 = 0.0f, acc1 = 0.0f;
    for (int base = s; base < e; base += 64) {
        const int nn = min(64, e - base);
        int ci = 0; float vf = 0.0f;
        if (lane < nn) {
            const float3 pk = *(const float3*)&packed[(size_t)3 * (base + lane)];
            ci = __builtin_bit_cast(int, pk.x);
            vf = pk.y;
        }
        for (int j = 0; j < nn; j += 8) {
#pragma unroll
            for (int q = 0; q < 4; ++q) {
                const int jj = j + 2 * q + g;
                const bool ok = jj < nn;
                const int idx = jj & 63;
                const int c = __shfl(ci, idx);
                const float v = __shfl(vf, idx);
                if (ok) {
                    const unsigned u = *(const unsigned*)(X + (size_t)c * 64 + ls * 2);
                    acc0 += v * bf_lo(u);
                    acc1 += v * bf_hi(u);
                }
            }
        }
    }
    acc0 += __shfl_xor(acc0, 32);
    acc1 += __shfl_xor(acc1, 32);

    if (lane < 32) {
        const float am = AM[r];
        const float o0 = fminf(fmaxf(acc0 * am + bias[2 * ls], 0.0f), 1e30f);
        const float o1 = fminf(fmaxf(acc1 * am + bias[2 * ls + 1], 0.0f), 1e30f);
        ((unsigned*)out)[(size_t)r * 32 + ls] = pack2bf(o0, o1);
    }
}

// ---------------- SpMM F=40 + log_softmax: 3 edges/wave ----------------

__launch_bounds__(256)
__global__ void spmm40_kernel(const float* __restrict__ packed,
                              const int* __restrict__ rp, const unsigned short* __restrict__ X,
                              const float* __restrict__ bias,
                              float* __restrict__ out, int n) {
    const int lane = threadIdx.x & 63;
    const int g = lane / 20;
    const int ls = lane - 20 * g;
    const bool active = g < 3;
    const int r = (int)((blockIdx.x * (unsigned)blockDim.x + threadIdx.x) >> 6);
    if (r >= n) return;
    const int s = __builtin_amdgcn_readfirstlane(rp[r]);
    const int e = __builtin_amdgcn_readfirstlane(rp[r + 1]);

    float acc0 = 0.0f, acc1 = 0.0f;
    for (int base = s; base < e; base += 64) {
        const int nn = min(64, e - base);
        int ci = 0; float vf = 0.0f;
        if (lane < nn) {
            const float3 pk = *(const float3*)&packed[(size_t)3 * (base + lane)];
            ci = __builtin_bit_cast(int, pk.x);
            vf = pk.z;                   // adj (not adjZ) values
        }
        for (int j = 0; j < nn; j += 12) {
#pragma unroll
            for (int q = 0; q < 4; ++q) {
                const int jj = j + 3 * q + g;
                const bool ok = active && jj < nn;
                const int idx = jj & 63;
                const int c = __shfl(ci, idx);
                const float v = __shfl(vf, idx);
                if (ok) {
                    const unsigned u = *(const unsigned*)(X + (size_t)c * 40 + ls * 2);
                    acc0 += v * bf_lo(u);
                    acc1 += v * bf_hi(u);
                }
            }
        }
    }
    {
        const float a1 = __shfl(acc0, (lane + 20) & 63);
        const float a2 = __shfl(acc0, (lane + 40) & 63);
        const float b1 = __shfl(acc1, (lane + 20) & 63);
        const float b2 = __shfl(acc1, (lane + 40) & 63);
        acc0 += a1 + a2;
        acc1 += b1 + b2;
    }

    const bool own = lane < 20;
    const float vv0 = own ? fminf(fmaxf(acc0 + bias[2 * ls], -1e30f), 1e30f) : -INFINITY;
    const float vv1 = own ? fminf(fmaxf(acc1 + bias[2 * ls + 1], -1e30f), 1e30f) : -INFINITY;
    float mx = fmaxf(vv0, vv1);
#pragma unroll
    for (int off = 32; off > 0; off >>= 1) mx = fmaxf(mx, __shfl_xor(mx, off));
    float sum = own ? (expf(vv0 - mx) + expf(vv1 - mx)) : 0.0f;
#pragma unroll
    for (int off = 32; off > 0; off >>= 1) sum += __shfl_xor(sum, off);
    if (own) {
        const float lse = mx + logf(sum);
        *(float2*)(out + (size_t)r * 40 + ls * 2) = make_float2(vv0 - lse, vv1 - lse);
    }
}

// ---------------- launch ----------------

extern "C" void kernel_launch(void* const* d_in, const int* in_sizes, int n_in,
                              void* d_out, int out_size, void* d_ws, size_t ws_size,
                              hipStream_t stream) {
    const float* x    = (const float*)d_in[0];
    const float* M    = (const float*)d_in[1];
    const float* AM   = (const float*)d_in[2];
    const float* adjv = (const float*)d_in[3];
    const float* adjZ = (const float*)d_in[4];
    const float* W0   = (const float*)d_in[5];
    const float* b0   = (const float*)d_in[6];
    const float* W1   = (const float*)d_in[7];
    const float* b1   = (const float*)d_in[8];
    const float* W2   = (const float*)d_in[9];
    const float* b2   = (const float*)d_in[10];
    const int* row    = (const int*)d_in[11];
    const int* col    = (const int*)d_in[12];
    float* out = (float*)d_out;

    const int n = in_sizes[1];   // N
    const int E = in_sizes[3];   // edges
    const int G = (E + EPB - 1) >> EPB_LOG2;    // hist chunks (196 @ E=800K)

    // flat workspace layout (~57MB of 256MB):
    char* p = (char*)d_ws;
    unsigned short* t_buf = (unsigned short*)p;  p += (size_t)n * 128 * 2;   // 12.8MB
    unsigned short* h_buf = (unsigned short*)p;  p += (size_t)n * 128 * 2;   // 12.8MB
    unsigned short* wt0   = (unsigned short*)p;  p += 128 * 128 * 2;
    unsigned short* wt1   = (unsigned short*)p;  p += 64 * 128 * 2;
    unsigned short* wt2   = (unsigned short*)p;  p += 48 * 64 * 2 + 64;
    unsigned short* cnt16 = (unsigned short*)p;  p += (size_t)G * n * 2;     // 19.6MB
    int* rp        = (int*)p;                    p += (size_t)(n + 1) * 4;
    int* bsums     = (int*)p;                    p += 64 * 4;
    unsigned short* pos_local = (unsigned short*)p;  p += (size_t)E * 2;     // 1.6MB
    float* packed  = (float*)p;                  /* E*3 floats, 9.6MB */

    const int prepBlocks = (128 * 128 + 64 * 128 + 48 * 64 + 255) / 256;
    const int gemmBlocks = (n + 63) / 64;
    const int nblk = (n + 1023) >> 10;  // 49; <=64 required by scan_top

    // CSR build (+W prep, +gemm0 fused into the scan launch)
    hist_prep<<<G + prepBlocks, 256, 0, stream>>>(row, cnt16, pos_local, n, E, G,
                                                  W0, W1, W2, wt0, wt1, wt2);
    scan_gemm0<<<nblk + gemmBlocks, 256, 0, stream>>>(cnt16, rp, bsums, n, G, nblk,
                                                      x, M, wt0, t_buf);
    scan_top<<<1, 64, 0, stream>>>(bsums, nblk);
    scan_add<<<(n + 255) / 256, 256, 0, stream>>>(rp, bsums, n, E);
    scatter_kernel<<<(E + 1023) / 1024, 256, 0, stream>>>(row, col, adjv, adjZ, rp, cnt16,
                                                          pos_local, packed, E, n);

    const int spmmBlocks = (n + 3) / 4;   // 4 rows (waves) per block

    // layer 0 aggregate: h_buf = M⊙relu(AM⊙agg+b0) bf16
    spmm128_kernel<<<spmmBlocks, 256, 0, stream>>>(packed, rp, t_buf, AM, M, b0, h_buf, n);
    // layer 1: t_buf = h_buf@W1 bf16 (M already folded)
    gemm_mfma<128, 64, 64, true, false><<<gemmBlocks, 256, 0, stream>>>(h_buf, nullptr, wt1,
                                                                        t_buf, n);
    spmm64_kernel<<<spmmBlocks, 256, 0, stream>>>(packed, rp, t_buf, AM, b1, h_buf, n);
    // layer 2: t_buf = h1@W2 bf16 (stride 40)
    gemm_mfma<64, 40, 48, true, false><<<gemmBlocks, 256, 0, stream>>>(h_buf, nullptr, wt2,
                                                                       t_buf, n);
    spmm40_kernel<<<spmmBlocks, 256, 0, stream>>>(packed, rp, t_buf, b2, out, n);
}

// Round 14
// 304.286 us; speedup vs baseline: 1.1446x; 1.0990x over previous
//
#include <hip/hip_runtime.h>
#include <hip/hip_bf16.h>
#include <math.h>

// PaGCN forward, restructured:
//   h0 = relu(AM ⊙ spmm(adjZ, (M⊙x)@W0) + b0)      (spmm gathers 128 bf16 feats)
//   h1 = relu(AM ⊙ spmm(adjZ, (M⊙h0)@W1) + b1)     (spmm gathers 64 bf16 feats)
//   out = log_softmax(spmm(adj, h1@W2) + b2)        (spmm gathers 40 bf16 feats)
//
// R14 == R13 resubmit (R13 hit a GPU-broker timeout; never executed).
// Hierarchical chunk scan. R12's scan walked G=196 chunks serially with
// 49 blocks (70us, HBM-latency-bound). Now G = 14 supers x 14 chunks:
//   Phase A (fused w/ gemm0): per (row-block, super) prefix over 14 chunks
//            in-place; super totals -> sup[14][N].
//   Phase B: prefix over 14 supers + row totals + block scan -> rp.
//   Scatter: pos = rp[r] + sup[g/14][r] + cnt16[g][r] + rank (sup L2-hot).
// Carried: LDS-atomic hist (G=196, saturating), ushort cnt16/pos_local,
// no-LDS MFMA gemms, bf16 gather targets, M folded into spmm128, multi-edge
// spmm40/64, 8-deep spmm128 bursts, NaN-laundering clamps.

typedef __attribute__((ext_vector_type(8))) short bf16x8;
typedef __attribute__((ext_vector_type(4))) float f32x4;

#define EPB_LOG2 12
#define EPB (1 << EPB_LOG2)   // 4096 edges per hist chunk
#define SUPW 14               // chunks per super-chunk

__device__ __forceinline__ float rl_f(float v, int j) {
    return __builtin_bit_cast(float,
        __builtin_amdgcn_readlane(__builtin_bit_cast(int, v), j));
}
__device__ __forceinline__ int rl_i(int v, int j) {
    return __builtin_amdgcn_readlane(v, j);
}
__device__ __forceinline__ unsigned short f2bf(float f) {
    unsigned u = __builtin_bit_cast(unsigned, f);
    u += 0x7fffu + ((u >> 16) & 1u);   // round-to-nearest-even
    return (unsigned short)(u >> 16);
}
__device__ __forceinline__ unsigned pack2bf(float lo, float hi) {
    return (unsigned)f2bf(lo) | ((unsigned)f2bf(hi) << 16);
}
__device__ __forceinline__ float bf_lo(unsigned u) {
    return __builtin_bit_cast(float, u << 16);
}
__device__ __forceinline__ float bf_hi(unsigned u) {
    return __builtin_bit_cast(float, u & 0xffff0000u);
}
__device__ __forceinline__ float clampf(float v) {
    return fminf(fmaxf(v, -1e30f), 1e30f);
}

// ---------------- MFMA GEMM body (no LDS, no barriers) ----------------
// A: lane supplies row m=lane&15, k=q*8..q*8+7 per 32-chunk; B: col n=lane&15;
// D: row=q*4+reg, col=lane&15.  (HW-verified fragment maps.)

template <int K, int COLS, int NTPAD, bool ABF16, bool MSCALE>
__device__ __forceinline__ void gemm_mfma_body(const void* __restrict__ Asrc,
                                               const float* __restrict__ Mv,
                                               const unsigned short* __restrict__ Wt,
                                               unsigned short* __restrict__ outp,
                                               int n, int bid) {
    constexpr int KS = K / 32;
    const int lane = threadIdx.x & 63;
    const int wid = threadIdx.x >> 6;
    const int m15 = lane & 15;
    const int q = lane >> 4;
    const int rA = bid * 64 + wid * 16 + m15;

    bf16x8 a[KS];
    if constexpr (ABF16) {
        const unsigned short* A = (const unsigned short*)Asrc;
#pragma unroll
        for (int ks = 0; ks < KS; ++ks) {
            uint4 z = make_uint4(0u, 0u, 0u, 0u);
            if (rA < n) z = *(const uint4*)(A + (size_t)rA * K + ks * 32 + q * 8);
            a[ks] = __builtin_bit_cast(bf16x8, z);
        }
    } else {
        const float* A = (const float*)Asrc;
        float m = 1.0f;
        if constexpr (MSCALE) { if (rA < n) m = Mv[rA]; }
#pragma unroll
        for (int ks = 0; ks < KS; ++ks) {
            float4 lo = make_float4(0.f, 0.f, 0.f, 0.f);
            float4 hi = make_float4(0.f, 0.f, 0.f, 0.f);
            if (rA < n) {
                lo = *(const float4*)(A + (size_t)rA * K + ks * 32 + q * 8);
                hi = *(const float4*)(A + (size_t)rA * K + ks * 32 + q * 8 + 4);
            }
            union { bf16x8 v; unsigned short u[8]; } pk;
            pk.u[0] = f2bf(lo.x * m); pk.u[1] = f2bf(lo.y * m);
            pk.u[2] = f2bf(lo.z * m); pk.u[3] = f2bf(lo.w * m);
            pk.u[4] = f2bf(hi.x * m); pk.u[5] = f2bf(hi.y * m);
            pk.u[6] = f2bf(hi.z * m); pk.u[7] = f2bf(hi.w * m);
            a[ks] = pk.v;
        }
    }

#pragma unroll
    for (int nt = 0; nt < NTPAD / 16; ++nt) {
        f32x4 acc = {0.f, 0.f, 0.f, 0.f};
        const int bn = nt * 16 + m15;
#pragma unroll
        for (int ks = 0; ks < KS; ++ks) {
            const uint4 z = *(const uint4*)(Wt + (size_t)bn * K + ks * 32 + q * 8);
            const bf16x8 b = __builtin_bit_cast(bf16x8, z);
            acc = __builtin_amdgcn_mfma_f32_16x16x32_bf16(a[ks], b, acc, 0, 0, 0);
        }
        const int gc = nt * 16 + m15;
#pragma unroll
        for (int rr = 0; rr < 4; ++rr) {
            const int gr = bid * 64 + wid * 16 + q * 4 + rr;
            bool ok = gr < n;
            if constexpr (NTPAD != COLS) ok = ok && (gc < COLS);
            if (ok) outp[(size_t)gr * COLS + gc] = f2bf(clampf(acc[rr]));
        }
    }
}

template <int K, int COLS, int NTPAD, bool ABF16, bool MSCALE>
__launch_bounds__(256)
__global__ void gemm_mfma(const void* __restrict__ A, const float* __restrict__ Mv,
                          const unsigned short* __restrict__ Wt,
                          unsigned short* __restrict__ out, int n) {
    gemm_mfma_body<K, COLS, NTPAD, ABF16, MSCALE>(A, Mv, Wt, out, n, blockIdx.x);
}

// ---------------- hist (LDS atomics) + fused W-prep ----------------

__launch_bounds__(256)
__global__ void hist_prep(const int* __restrict__ row, unsigned short* __restrict__ cnt16,
                          unsigned short* __restrict__ pos_local, int n, int E, int G,
                          const float* __restrict__ W0, const float* __restrict__ W1,
                          const float* __restrict__ W2,
                          unsigned short* __restrict__ wt0, unsigned short* __restrict__ wt1,
                          unsigned short* __restrict__ wt2) {
    __shared__ int lds[12544];                 // 50.2KB; supports n <= 50176
    const int b = blockIdx.x;
    if (b >= G) {
        int idx = (b - G) * 256 + threadIdx.x;
        if (idx < 128 * 128) {                       // wt0: [128][128]
            int nn = idx >> 7, k = idx & 127;
            wt0[idx] = f2bf(W0[k * 128 + nn]);
        }
        idx -= 128 * 128;
        if (idx >= 0 && idx < 64 * 128) {            // wt1: [64][128]
            int nn = idx >> 7, k = idx & 127;
            wt1[idx] = f2bf(W1[k * 64 + nn]);
        }
        idx -= 64 * 128;
        if (idx >= 0 && idx < 48 * 64) {             // wt2: [48][64], n>=40 zero
            int nn = idx >> 6, k = idx & 63;
            wt2[idx] = (nn < 40) ? f2bf(W2[k * 40 + nn]) : (unsigned short)0;
        }
        return;
    }

    const int g = b;
    const int t = threadIdx.x;
    const int e0 = g << EPB_LOG2;
    const int e1 = min(e0 + EPB, E);
    const int halfn = (n + 1) >> 1;            // rows per pass

    for (int pass = 0; pass < 2; ++pass) {
        const int rlo = pass * halfn;
        const int rhi = min(rlo + halfn, n);
        const int bins = (rhi - rlo + 1) >> 1;
        for (int i = t; i < bins; i += 256) lds[i] = 0;
        __syncthreads();
        for (int e = e0 + t; e < e1; e += 256) {
            const int r = row[e];
            if (r >= rlo && r < rhi) {
                const int lr = r - rlo;
                const int old = atomicAdd(&lds[lr >> 1], (lr & 1) ? 0x10000 : 1);
                pos_local[e] = (unsigned short)((lr & 1) ? (old >> 16) : (old & 0xffff));
            }
        }
        __syncthreads();
        for (int i = t; i < rhi - rlo; i += 256) {
            const int v = lds[i >> 1];
            cnt16[(size_t)g * n + rlo + i] =
                (unsigned short)((i & 1) ? (v >> 16) : (v & 0xffff));
        }
        __syncthreads();
    }
}

// ---------------- Phase A: prefix within super-chunk (fused gemm0) ----------------
// Blocks [0, nA): b -> (rb, s); prefix cnt16[g][i] over the 14 chunks of
// super s in-place; totals -> sup[s][i].  Blocks [nA,...): gemm0.

__launch_bounds__(256)
__global__ void scanA_gemm0(unsigned short* __restrict__ cnt16,
                            unsigned short* __restrict__ sup,
                            int n, int G, int SC, int nA,
                            const float* __restrict__ x, const float* __restrict__ Mv,
                            const unsigned short* __restrict__ wt0,
                            unsigned short* __restrict__ t_buf) {
    const int b = blockIdx.x;
    if (b >= nA) {
        gemm_mfma_body<128, 128, 128, false, true>(x, Mv, wt0, t_buf, n, b - nA);
        return;
    }
    const int s = b % SC;
    const int rb = b / SC;
    const int t = threadIdx.x;
    const int base = rb * 1024 + t * 4;
    if (base >= n) return;

    if (base + 3 < n) {
        int v0 = 0, v1 = 0, v2 = 0, v3 = 0;
        for (int c = 0; c < SUPW; ++c) {
            const int g = s * SUPW + c;
            if (g >= G) break;
            ushort4* p = (ushort4*)&cnt16[(size_t)g * n + base];
            const ushort4 cc = *p;
            ushort4 w;
            w.x = (unsigned short)v0; w.y = (unsigned short)v1;
            w.z = (unsigned short)v2; w.w = (unsigned short)v3;
            *p = w;
            v0 += cc.x; v1 += cc.y; v2 += cc.z; v3 += cc.w;
        }
        ushort4 o;
        o.x = (unsigned short)v0; o.y = (unsigned short)v1;
        o.z = (unsigned short)v2; o.w = (unsigned short)v3;
        *(ushort4*)&sup[(size_t)s * n + base] = o;
    } else {
        int vv[4] = {0, 0, 0, 0};
        for (int c = 0; c < SUPW; ++c) {
            const int g = s * SUPW + c;
            if (g >= G) break;
#pragma unroll
            for (int i = 0; i < 4; ++i) {
                const int idx = base + i;
                if (idx < n) {
                    const int cc = cnt16[(size_t)g * n + idx];
                    cnt16[(size_t)g * n + idx] = (unsigned short)vv[i];
                    vv[i] += cc;
                }
            }
        }
#pragma unroll
        for (int i = 0; i < 4; ++i)
            if (base + i < n) sup[(size_t)s * n + base + i] = (unsigned short)vv[i];
    }
}

// ---------------- Phase B: prefix over supers + row totals + block scan ----------------

__launch_bounds__(256)
__global__ void scanB(unsigned short* __restrict__ sup, int* __restrict__ rp,
                      int* __restrict__ bsums, int n, int SC) {
    __shared__ int sdata[256];
    const int t = threadIdx.x;
    const int base = blockIdx.x * 1024 + t * 4;
    int v0 = 0, v1 = 0, v2 = 0, v3 = 0;
    if (base + 3 < n) {
        for (int s = 0; s < SC; ++s) {
            ushort4* p = (ushort4*)&sup[(size_t)s * n + base];
            const ushort4 c = *p;
            ushort4 w;
            w.x = (unsigned short)v0; w.y = (unsigned short)v1;
            w.z = (unsigned short)v2; w.w = (unsigned short)v3;
            *p = w;
            v0 += c.x; v1 += c.y; v2 += c.z; v3 += c.w;
        }
    } else {
        int vv[4] = {0, 0, 0, 0};
        for (int s = 0; s < SC; ++s) {
#pragma unroll
            for (int i = 0; i < 4; ++i) {
                const int idx = base + i;
                if (idx < n) {
                    const int c = sup[(size_t)s * n + idx];
                    sup[(size_t)s * n + idx] = (unsigned short)vv[i];
                    vv[i] += c;
                }
            }
        }
        v0 = vv[0]; v1 = vv[1]; v2 = vv[2]; v3 = vv[3];
    }
    const int tsum = v0 + v1 + v2 + v3;
    sdata[t] = tsum;
    __syncthreads();
    for (int off = 1; off < 256; off <<= 1) {
        int xx = (t >= off) ? sdata[t - off] : 0;
        __syncthreads();
        sdata[t] += xx;
        __syncthreads();
    }
    int run = sdata[t] - tsum;
    if (t == 255) bsums[blockIdx.x] = sdata[t];
    if (base < n) rp[base] = run;
    run += v0;
    if (base + 1 < n) rp[base + 1] = run;
    run += v1;
    if (base + 2 < n) rp[base + 2] = run;
    run += v2;
    if (base + 3 < n) rp[base + 3] = run;
}

__global__ void scan_top(int* __restrict__ bs, int nb) {
    int t = threadIdx.x;
    int orig = (t < nb) ? bs[t] : 0;
    int v = orig;
#pragma unroll
    for (int off = 1; off < 64; off <<= 1) {
        int x = __shfl_up(v, off);
        if (t >= off) v += x;
    }
    if (t < nb) bs[t] = v - orig;
}

__global__ void scan_add(int* __restrict__ rp, const int* __restrict__ bs,
                         int n, int total) {
    int i = blockIdx.x * blockDim.x + threadIdx.x;
    if (i < n) rp[i] += bs[i >> 10];
    if (i == 0) rp[n] = total;
}

// ---------------- scatter (atomic-free, 4 edges/thread) ----------------
// pos = rp[r] + sup[g/14][r] + cnt16[g][r] + rank

__global__ void scatter_kernel(const int* __restrict__ row, const int* __restrict__ col,
                               const float* __restrict__ vA, const float* __restrict__ vZ,
                               const int* __restrict__ rp, const unsigned short* __restrict__ cnt16,
                               const unsigned short* __restrict__ sup,
                               const unsigned short* __restrict__ pos_local,
                               float* __restrict__ packed, int E, int n) {
    const int base = blockIdx.x * 1024 + threadIdx.x;
#pragma unroll
    for (int u = 0; u < 4; ++u) {
        const int e = base + u * 256;
        if (e >= E) continue;
        const int g = e >> EPB_LOG2;
        const int s = g / SUPW;
        const int r = row[e];
        const int pos = rp[r] + (int)sup[(size_t)s * n + r] +
                        (int)cnt16[(size_t)g * n + r] + (int)pos_local[e];
        float3 pk;
        pk.x = __int_as_float(col[e]);
        pk.y = vZ[e];
        pk.z = vA[e];
        *(float3*)&packed[(size_t)3 * pos] = pk;
    }
}

// ---------------- SpMM F=128: wave/row, 8-deep bursts; out = M⊙relu(...) bf16 ----------------

__launch_bounds__(256)
__global__ void spmm128_kernel(const float* __restrict__ packed,
                               const int* __restrict__ rp, const unsigned short* __restrict__ X,
                               const float* __restrict__ AM, const float* __restrict__ Mv,
                               const float* __restrict__ bias,
                               unsigned short* __restrict__ out, int n) {
    const int lane = threadIdx.x & 63;
    const int r = (int)((blockIdx.x * (unsigned)blockDim.x + threadIdx.x) >> 6);
    if (r >= n) return;
    const int s = __builtin_amdgcn_readfirstlane(rp[r]);
    const int e = __builtin_amdgcn_readfirstlane(rp[r + 1]);

    float acc0 = 0.0f, acc1 = 0.0f;
    for (int base = s; base < e; base += 64) {
        const int nn = min(64, e - base);
        int ci = 0; float vf = 0.0f;
        if (lane < nn) {
            const float3 pk = *(const float3*)&packed[(size_t)3 * (base + lane)];
            ci = __builtin_bit_cast(int, pk.x);
            vf = pk.y;
        }
        int j = 0;
        for (; j + 8 <= nn; j += 8) {
            unsigned u[8];
#pragma unroll
            for (int q = 0; q < 8; ++q) {
                const int cq = rl_i(ci, j + q);
                u[q] = *(const unsigned*)(X + (size_t)cq * 128 + lane * 2);
            }
#pragma unroll
            for (int q = 0; q < 8; ++q) {
                const float vq = rl_f(vf, j + q);
                acc0 += vq * bf_lo(u[q]);
                acc1 += vq * bf_hi(u[q]);
            }
        }
        for (; j < nn; ++j) {
            const int cq = rl_i(ci, j);
            const float vq = rl_f(vf, j);
            const unsigned u = *(const unsigned*)(X + (size_t)cq * 128 + lane * 2);
            acc0 += vq * bf_lo(u);
            acc1 += vq * bf_hi(u);
        }
    }

    const float am = AM[r];
    const float mr = Mv[r];   // fold M (>=0): M⊙relu(y) = relu(M⊙y)
    const float o0 = fminf(fmaxf((acc0 * am + bias[2 * lane]) * mr, 0.0f), 1e30f);
    const float o1 = fminf(fmaxf((acc1 * am + bias[2 * lane + 1]) * mr, 0.0f), 1e30f);
    ((unsigned*)out)[(size_t)r * 64 + lane] = pack2bf(o0, o1);
}

// ---------------- SpMM F=64: 2 edges/wave; out = relu(...) bf16 ----------------

__launch_bounds__(256)
__global__ void spmm64_kernel(const float* __restrict__ packed,
                              const int* __restrict__ rp, const unsigned short* __restrict__ X,
                              const float* __restrict__ AM, const float* __restrict__ bias,
                              unsigned short* __restrict__ out, int n) {
    const int lane = threadIdx.x & 63;
    const int g = lane >> 5;
    const int ls = lane & 31;
    const int r = (int)((blockIdx.x * (unsigned)blockDim.x + threadIdx.x) >> 6);
    if (r >= n) return;
    const int s = __builtin_amdgcn_readfirstlane(rp[r]);
    const int e = __builtin_amdgcn_readfirstlane(rp[r + 1]);

    float acc0 = 0.0f, acc1 = 0.0f;
    for (int base = s; base < e; base += 64) {
        const int nn = min(64, e - base);
        int ci = 0; float vf = 0.0f;
        if (lane < nn) {
            const float3 pk = *(const float3*)&packed[(size_t)3 * (base + lane)];
            ci = __builtin_bit_cast(int, pk.x);
            vf = pk.y;
        }
        for (int j = 0; j < nn; j += 8) {
#pragma unroll
            for (int q = 0; q < 4; ++q) {
                const int jj = j + 2 * q + g;
                const bool ok = jj < nn;
                const int idx = jj & 63;
                const int c = __shfl(ci, idx);
                const float v = __shfl(vf, idx);
                if (ok) {
                    const unsigned u = *(const unsigned*)(X + (size_t)c * 64 + ls * 2);
                    acc0 += v * bf_lo(u);
                    acc1 += v * bf_hi(u);
                }
            }
        }
    }
    acc0 += __shfl_xor(acc0, 32);
    acc1 += __shfl_xor(acc1, 32);

    if (lane < 32) {
        const float am = AM[r];
        const float o0 = fminf(fmaxf(acc0 * am + bias[2 * ls], 0.0f), 1e30f);
        const float o1 = fminf(fmaxf(acc1 * am + bias[2 * ls + 1], 0.0f), 1e30f);
        ((unsigned*)out)[(size_t)r * 32 + ls] = pack2bf(o0, o1);
    }
}

// ---------------- SpMM F=40 + log_softmax: 3 edges/wave ----------------

__launch_bounds__(256)
__global__ void spmm40_kernel(const float* __restrict__ packed,
                              const int* __restrict__ rp, const unsigned short* __restrict__ X,
                              const float* __restrict__ bias,
                              float* __restrict__ out, int n) {
    const int lane = threadIdx.x & 63;
    const int g = lane / 20;
    const int ls = lane - 20 * g;
    const bool active = g < 3;
    const int r = (int)((blockIdx.x * (unsigned)blockDim.x + threadIdx.x) >> 6);
    if (r >= n) return;
    const int s = __builtin_amdgcn_readfirstlane(rp[r]);
    const int e = __builtin_amdgcn_readfirstlane(rp[r + 1]);

    float acc0 = 0.0f, acc1 = 0.0f;
    for (int base = s; base < e; base += 64) {
        const int nn = min(64, e - base);
        int ci = 0; float vf = 0.0f;
        if (lane < nn) {
            const float3 pk = *(const float3*)&packed[(size_t)3 * (base + lane)];
            ci = __builtin_bit_cast(int, pk.x);
            vf = pk.z;                   // adj (not adjZ) values
        }
        for (int j = 0; j < nn; j += 12) {
#pragma unroll
            for (int q = 0; q < 4; ++q) {
                const int jj = j + 3 * q + g;
                const bool ok = active && jj < nn;
                const int idx = jj & 63;
                const int c = __shfl(ci, idx);
                const float v = __shfl(vf, idx);
                if (ok) {
                    const unsigned u = *(const unsigned*)(X + (size_t)c * 40 + ls * 2);
                    acc0 += v * bf_lo(u);
                    acc1 += v * bf_hi(u);
                }
            }
        }
    }
    {
        const float a1 = __shfl(acc0, (lane + 20) & 63);
        const float a2 = __shfl(acc0, (lane + 40) & 63);
        const float b1 = __shfl(acc1, (lane + 20) & 63);
        const float b2 = __shfl(acc1, (lane + 40) & 63);
        acc0 += a1 + a2;
        acc1 += b1 + b2;
    }

    const bool own = lane < 20;
    const float vv0 = own ? fminf(fmaxf(acc0 + bias[2 * ls], -1e30f), 1e30f) : -INFINITY;
    const float vv1 = own ? fminf(fmaxf(acc1 + bias[2 * ls + 1], -1e30f), 1e30f) : -INFINITY;
    float mx = fmaxf(vv0, vv1);
#pragma unroll
    for (int off = 32; off > 0; off >>= 1) mx = fmaxf(mx, __shfl_xor(mx, off));
    float sum = own ? (expf(vv0 - mx) + expf(vv1 - mx)) : 0.0f;
#pragma unroll
    for (int off = 32; off > 0; off >>= 1) sum += __shfl_xor(sum, off);
    if (own) {
        const float lse = mx + logf(sum);
        *(float2*)(out + (size_t)r * 40 + ls * 2) = make_float2(vv0 - lse, vv1 - lse);
    }
}

// ---------------- launch ----------------

extern "C" void kernel_launch(void* const* d_in, const int* in_sizes, int n_in,
                              void* d_out, int out_size, void* d_ws, size_t ws_size,
                              hipStream_t stream) {
    const float* x    = (const float*)d_in[0];
    const float* M    = (const float*)d_in[1];
    const float* AM   = (const float*)d_in[2];
    const float* adjv = (const float*)d_in[3];
    const float* adjZ = (const float*)d_in[4];
    const float* W0   = (const float*)d_in[5];
    const float* b0   = (const float*)d_in[6];
    const float* W1   = (const float*)d_in[7];
    const float* b1   = (const float*)d_in[8];
    const float* W2   = (const float*)d_in[9];
    const float* b2   = (const float*)d_in[10];
    const int* row    = (const int*)d_in[11];
    const int* col    = (const int*)d_in[12];
    float* out = (float*)d_out;

    const int n = in_sizes[1];   // N
    const int E = in_sizes[3];   // edges
    const int G = (E + EPB - 1) >> EPB_LOG2;    // hist chunks (196 @ E=800K)
    const int SC = (G + SUPW - 1) / SUPW;       // super-chunks (14)

    // flat workspace layout (~59MB of 256MB):
    char* p = (char*)d_ws;
    unsigned short* t_buf = (unsigned short*)p;  p += (size_t)n * 128 * 2;   // 12.8MB
    unsigned short* h_buf = (unsigned short*)p;  p += (size_t)n * 128 * 2;   // 12.8MB
    unsigned short* wt0   = (unsigned short*)p;  p += 128 * 128 * 2;
    unsigned short* wt1   = (unsigned short*)p;  p += 64 * 128 * 2;
    unsigned short* wt2   = (unsigned short*)p;  p += 48 * 64 * 2 + 64;
    unsigned short* cnt16 = (unsigned short*)p;  p += (size_t)G * n * 2;     // 19.6MB
    unsigned short* sup   = (unsigned short*)p;  p += (size_t)SC * n * 2;    // 1.4MB
    int* rp        = (int*)p;                    p += (size_t)(n + 1) * 4;
    int* bsums     = (int*)p;                    p += 64 * 4;
    unsigned short* pos_local = (unsigned short*)p;  p += (size_t)E * 2;     // 1.6MB
    float* packed  = (float*)p;                  /* E*3 floats, 9.6MB */

    const int prepBlocks = (128 * 128 + 64 * 128 + 48 * 64 + 255) / 256;
    const int gemmBlocks = (n + 63) / 64;
    const int nblk = (n + 1023) >> 10;  // 49; <=64 required by scan_top
    const int nA = nblk * SC;           // phase-A blocks (686)

    // CSR build (+W prep fused into hist; gemm0 fused into phase A)
    hist_prep<<<G + prepBlocks, 256, 0, stream>>>(row, cnt16, pos_local, n, E, G,
                                                  W0, W1, W2, wt0, wt1, wt2);
    scanA_gemm0<<<nA + gemmBlocks, 256, 0, stream>>>(cnt16, sup, n, G, SC, nA,
                                                     x, M, wt0, t_buf);
    scanB<<<nblk, 256, 0, stream>>>(sup, rp, bsums, n, SC);
    scan_top<<<1, 64, 0, stream>>>(bsums, nblk);
    scan_add<<<(n + 255) / 256, 256, 0, stream>>>(rp, bsums, n, E);
    scatter_kernel<<<(E + 1023) / 1024, 256, 0, stream>>>(row, col, adjv, adjZ, rp, cnt16,
                                                          sup, pos_local, packed, E, n);

    const int spmmBlocks = (n + 3) / 4;   // 4 rows (waves) per block

    // layer 0 aggregate: h_buf = M⊙relu(AM⊙agg+b0) bf16
    spmm128_kernel<<<spmmBlocks, 256, 0, stream>>>(packed, rp, t_buf, AM, M, b0, h_buf, n);
    // layer 1: t_buf = h_buf@W1 bf16 (M already folded)
    gemm_mfma<128, 64, 64, true, false><<<gemmBlocks, 256, 0, stream>>>(h_buf, nullptr, wt1,
                                                                        t_buf, n);
    spmm64_kernel<<<spmmBlocks, 256, 0, stream>>>(packed, rp, t_buf, AM, b1, h_buf, n);
    // layer 2: t_buf = h1@W2 bf16 (stride 40)
    gemm_mfma<64, 40, 48, true, false><<<gemmBlocks, 256, 0, stream>>>(h_buf, nullptr, wt2,
                                                                       t_buf, n);
    spmm40_kernel<<<spmmBlocks, 256, 0, stream>>>(packed, rp, t_buf, b2, out, n);
}